// Round 5
// baseline (724.001 us; speedup 1.0000x reference)
//
#include <hip/hip_runtime.h>
#include <stdint.h>

typedef unsigned short u16;
typedef unsigned int   u32;

typedef __attribute__((ext_vector_type(8))) short bf16x8;
typedef __attribute__((ext_vector_type(4))) float f32x4;

#define NNODES 8000
#define EDG    64000
#define KLIN   384           /* concat padded k: 5*72 + 24 tail */
#define NCHK   1536          /* chunks per node row (48 slices * 32 b) */
#define ROWB   24576         /* bytes per node row */
#define ROWU16 12288
#define HXROW  512000
#define INROW  16000

__device__ __forceinline__ u32 f2bf(float f){
    u32 u = __float_as_uint(f);
    return (u + 0x7FFFu + ((u >> 16) & 1u)) >> 16;   // RNE
}
__device__ __forceinline__ float bfu(u16 s){ return __uint_as_float(((u32)s) << 16); }
__device__ __forceinline__ float lo16(u32 u){ return __uint_as_float(u << 16); }
__device__ __forceinline__ float hi16(u32 u){ return __uint_as_float(u & 0xFFFF0000u); }
__device__ __forceinline__ float sigm(float x){ return 1.f / (1.f + __expf(-x)); }

// ---------------- CSR build for support 0 ----------------
__global__ void hist_k(const int* __restrict__ rows, int* __restrict__ counts){
    int e = blockIdx.x * 256 + threadIdx.x;
    if (e < EDG) atomicAdd(&counts[rows[e]], 1);
}

__global__ __launch_bounds__(256) void scan_k(const int* __restrict__ counts,
                                              int* __restrict__ row_ptr,
                                              int* __restrict__ cursor){
    __shared__ int part[256];
    int t = threadIdx.x;
    int s = 0;
    for (int i = 0; i < 32; ++i){ int r = t*32 + i; if (r < NNODES) s += counts[r]; }
    part[t] = s;
    __syncthreads();
    if (t == 0){
        int run = 0;
        for (int i = 0; i < 256; ++i){ int v = part[i]; part[i] = run; run += v; }
    }
    __syncthreads();
    int run = part[t];
    for (int i = 0; i < 32; ++i){
        int r = t*32 + i;
        if (r < NNODES){ row_ptr[r] = run; cursor[r] = run; run += counts[r]; }
    }
    if (t == 255) row_ptr[NNODES] = run;
}

__global__ void scatter_k(const int* __restrict__ rows, const int* __restrict__ cols,
                          const float* __restrict__ vals, int* __restrict__ cursor,
                          int* __restrict__ cs, float* __restrict__ vs){
    int e = blockIdx.x * 256 + threadIdx.x;
    if (e < EDG){
        int r = rows[e];
        int slot = atomicAdd(&cursor[r], 1);
        cs[slot] = cols[e];
        vs[slot] = vals[e];
    }
}

// ---------------- W pre-transpose: Wt[c][384]; kl -> m = kl/72, f = kl%72 ----------------
__global__ void prep_w_k(const float* __restrict__ W_ru, const float* __restrict__ W_c,
                         u16* __restrict__ Wt_ru, u16* __restrict__ Wt_c){
    int id = blockIdx.x * 256 + threadIdx.x;
    if (id < 128*KLIN){
        int c = id / KLIN, kl = id - c*KLIN;
        int m = kl / 72, f = kl - m*72;
        u16 v = 0;
        if (m < 5 && f < 66) v = (u16)f2bf(W_ru[(f*5 + m)*128 + c]);
        Wt_ru[id] = v;
    }
    int id2 = id - 128*KLIN;
    if (id2 >= 0 && id2 < 64*KLIN){
        int c = id2 / KLIN, kl = id2 - c*KLIN;
        int m = kl / 72, f = kl - m*72;
        u16 v = 0;
        if (m < 5 && f < 66) v = (u16)f2bf(W_c[(f*5 + m)*64 + c]);
        Wt_c[id2] = v;
    }
}

// ---------------- build x0 into concat slices 0..8; zero tail slices 45..47 ----------------
__global__ __launch_bounds__(256) void build_x0_k(const float* __restrict__ inputs,
                                                  const float* __restrict__ hx,
                                                  u16* __restrict__ X){
    __shared__ float sl[32*72];
    int n = blockIdx.x, t = threadIdx.x;
    #pragma unroll
    for (int i = 0; i < 8; ++i){
        int idx = t + i*256;                // 2048 hx elems
        int b = idx >> 6, f = idx & 63;
        sl[b*72 + 2 + f] = hx[b*HXROW + n*64 + f];
    }
    if (t < 64){
        int b = t >> 1, d = t & 1;
        sl[b*72 + d] = inputs[b*INROW + n*2 + d];
    }
    if (t < 192){
        int b = t / 6, k = t - b*6;
        sl[b*72 + 66 + k] = 0.f;
    }
    __syncthreads();
    uint4* xr = (uint4*)(X + (size_t)n*ROWU16);
    #pragma unroll
    for (int i = 0; i < 2; ++i){
        int j = t + i*256;
        if (j < 288){
            int b = j & 31, s = j >> 5;
            const float* p = &sl[b*72 + s*8];
            uint4 o;
            o.x = f2bf(p[0]) | (f2bf(p[1]) << 16);
            o.y = f2bf(p[2]) | (f2bf(p[3]) << 16);
            o.z = f2bf(p[4]) | (f2bf(p[5]) << 16);
            o.w = f2bf(p[6]) | (f2bf(p[7]) << 16);
            xr[j] = o;
        }
    }
    if (t < 96){
        uint4 z; z.x = z.y = z.z = z.w = 0;
        xr[1440 + t] = z;    // slices 45..47 zero (k-tail)
    }
}

__device__ __forceinline__ void acc8(float* a, uint4 q, float v){
    a[0] += v*lo16(q.x); a[1] += v*hi16(q.x);
    a[2] += v*lo16(q.y); a[3] += v*hi16(q.y);
    a[4] += v*lo16(q.z); a[5] += v*hi16(q.z);
    a[6] += v*lo16(q.w); a[7] += v*hi16(q.w);
}
__device__ __forceinline__ uint4 pack8(const float* a){
    uint4 o;
    o.x = f2bf(a[0]) | (f2bf(a[1]) << 16);
    o.y = f2bf(a[2]) | (f2bf(a[3]) << 16);
    o.z = f2bf(a[4]) | (f2bf(a[5]) << 16);
    o.w = f2bf(a[6]) | (f2bf(a[7]) << 16);
    return o;
}

// ---------------- fused diffusion level: two matrices per launch (grid halves) ----------------
// thread: (node, slice s 0..8, bpair 0..15) handles chunks (s,bp) and (s,bp+16)
__global__ __launch_bounds__(256) void diff_k(u16* X,
                                              const int* __restrict__ rp,
                                              const int* __restrict__ c0, const float* __restrict__ v0,
                                              const int* __restrict__ c1, const float* __restrict__ v1,
                                              int srcA, int dstA, int srcB, int dstB, int lvl2){
    int blk = blockIdx.x;
    int matB = (blk >= 4500) ? 1 : 0;
    int id = (blk - matB*4500)*256 + threadIdx.x;     // 0..1,151,999
    int n = id / 144;
    int rr = id - n*144;
    int s = rr >> 4, bp = rr & 15;
    int src = matB ? srcB : srcA;
    int dst = matB ? dstB : dstA;
    const int* cc; const float* vv; int start, end;
    if (matB){ cc = c1; vv = v1; start = n*8; end = start + 8; }
    else     { cc = c0; vv = v0; start = rp[n]; end = rp[n+1]; }

    const uint4* xb = (const uint4*)X;
    int co0 = (src + s)*32 + bp;
    int co1 = co0 + 16;

    float a0[8] = {0,0,0,0,0,0,0,0};
    float a1[8] = {0,0,0,0,0,0,0,0};
    int e = start;
    for (; e + 8 <= end; e += 8){
        uint4 qa[8], qb[8]; float wv[8];
        #pragma unroll
        for (int i = 0; i < 8; ++i){
            int c = cc[e+i]; wv[i] = vv[e+i];
            size_t rb = (size_t)c*NCHK;
            qa[i] = xb[rb + co0];
            qb[i] = xb[rb + co1];
        }
        #pragma unroll
        for (int i = 0; i < 8; ++i){ acc8(a0, qa[i], wv[i]); acc8(a1, qb[i], wv[i]); }
    }
    for (; e < end; ++e){
        int c = cc[e]; float v = vv[e];
        size_t rb = (size_t)c*NCHK;
        acc8(a0, xb[rb + co0], v);
        acc8(a1, xb[rb + co1], v);
    }
    if (lvl2){
        uint4 p0 = xb[(size_t)n*NCHK + s*32 + bp];
        uint4 p1 = xb[(size_t)n*NCHK + s*32 + bp + 16];
        float pa[8] = { lo16(p0.x), hi16(p0.x), lo16(p0.y), hi16(p0.y),
                        lo16(p0.z), hi16(p0.z), lo16(p0.w), hi16(p0.w) };
        float pb[8] = { lo16(p1.x), hi16(p1.x), lo16(p1.y), hi16(p1.y),
                        lo16(p1.z), hi16(p1.z), lo16(p1.w), hi16(p1.w) };
        #pragma unroll
        for (int i = 0; i < 8; ++i){ a0[i] = 2.f*a0[i] - pa[i]; a1[i] = 2.f*a1[i] - pb[i]; }
    }
    uint4* yb = (uint4*)X;
    yb[(size_t)n*NCHK + (dst + s)*32 + bp]      = pack8(a0);
    yb[(size_t)n*NCHK + (dst + s)*32 + bp + 16] = pack8(a1);
}

// ---------------- DMA stage of one k-step (16 KB = 8 nodes x 2 KB) ----------------
__device__ __forceinline__ void stage_step(const char* xbase, int j, char* lbase, int t){
    int w = t >> 6, lane = t & 63;
    #pragma unroll
    for (int i = 0; i < 4; ++i){
        int p = w*4 + i;          // 0..15
        int nd = p >> 1, h = p & 1;
        const char* g = xbase + nd*ROWB + j*2048 + h*1024 + lane*16;
        char* l = lbase + nd*2048 + h*1024 + lane*16;
        __builtin_amdgcn_global_load_lds(
            (const __attribute__((address_space(1))) u32*)g,
            (__attribute__((address_space(3))) u32*)l, 16, 0, 0);
    }
}

// ---------------- GEMM1: sigmoid(Xc@W_ru + b); U out; X slices 0..8 state <- r*hx ----------------
// block = 8 nodes (256 rows), 4 waves; wave w = rows [w*64, w*64+64) x 128 cols
__global__ __launch_bounds__(256, 2) void gemm_ru_k(
        u16* X, const u16* __restrict__ Wt, const float* __restrict__ b_ru,
        u16* __restrict__ U){
    __shared__ u16 sA[18432];    // staging: 2 x 8192 u16; epilogue: 8 nodes x 2304 u16
    const int t = threadIdx.x;
    const int lane = t & 63, w = t >> 6;
    const int cIn = lane & 15, q = lane >> 4;
    const int node0 = blockIdx.x * 8;
    const char* xbase = (const char*)X + (size_t)node0*ROWB;

    f32x4 acc[4][8];
    const f32x4 z4 = {0.f,0.f,0.f,0.f};
    #pragma unroll
    for (int rt = 0; rt < 4; ++rt)
        #pragma unroll
        for (int ct = 0; ct < 8; ++ct) acc[rt][ct] = z4;

    bf16x8 cb[8], nb[8];
    stage_step(xbase, 0, (char*)sA, t);
    #pragma unroll
    for (int ct = 0; ct < 8; ++ct)
        cb[ct] = *(const bf16x8*)&Wt[(ct*16 + cIn)*KLIN + q*8];
    __syncthreads();

    for (int j = 0; j < 12; ++j){
        const int cur = j & 1;
        if (j < 11){
            stage_step(xbase, j+1, (char*)sA + (cur^1)*16384, t);
            #pragma unroll
            for (int ct = 0; ct < 8; ++ct)
                nb[ct] = *(const bf16x8*)&Wt[(ct*16 + cIn)*KLIN + (j+1)*32 + q*8];
        }
        const u16* As = sA + cur*8192;
        #pragma unroll
        for (int rt = 0; rt < 4; ++rt){
            int nd = w*2 + (rt >> 1);
            int b  = (rt & 1)*16 + cIn;
            bf16x8 a = *(const bf16x8*)&As[nd*1024 + (q*32 + b)*8];
            #pragma unroll
            for (int ct = 0; ct < 8; ++ct)
                acc[rt][ct] = __builtin_amdgcn_mfma_f32_16x16x32_bf16(a, cb[ct], acc[rt][ct], 0,0,0);
        }
        #pragma unroll
        for (int ct = 0; ct < 8; ++ct) cb[ct] = nb[ct];
        __syncthreads();
    }

    // epilogue: load 8-node state region (slices 0..8) into LDS, RMW, store back
    uint4* eL = (uint4*)sA;
    #pragma unroll
    for (int i = 0; i < 9; ++i){
        int idx = t + i*256;                // 0..2303
        int nd = idx / 288, c = idx - nd*288;
        eL[idx] = *(const uint4*)(xbase + (size_t)nd*ROWB + c*16);
    }
    __syncthreads();
    #pragma unroll
    for (int ct = 0; ct < 8; ++ct){
        int col = ct*16 + cIn;
        float bias = b_ru[col];
        #pragma unroll
        for (int rt = 0; rt < 4; ++rt){
            int nd = w*2 + (rt >> 1);
            int b0 = (rt & 1)*16 + q*4;
            f32x4 d = acc[rt][ct];
            if (ct < 4){
                int fp = col + 2;
                int s = fp >> 3, off = fp & 7;
                #pragma unroll
                for (int i = 0; i < 4; ++i){
                    int li = (nd*288 + s*32 + b0 + i)*8 + off;
                    float h = bfu(sA[li]);
                    sA[li] = (u16)f2bf(sigm(d[i] + bias) * h);
                }
            } else {
                int node = node0 + nd;
                uint2 pk;
                float v0 = sigm(d[0] + bias), v1 = sigm(d[1] + bias);
                float v2 = sigm(d[2] + bias), v3 = sigm(d[3] + bias);
                pk.x = f2bf(v0) | (f2bf(v1) << 16);
                pk.y = f2bf(v2) | (f2bf(v3) << 16);
                *(uint2*)&U[(size_t)node*2048 + (col - 64)*32 + b0] = pk;
            }
        }
    }
    __syncthreads();
    #pragma unroll
    for (int i = 0; i < 9; ++i){
        int idx = t + i*256;
        int nd = idx / 288, c = idx - nd*288;
        *(uint4*)((char*)X + (size_t)(node0 + nd)*ROWB + c*16) = eL[idx];
    }
}

// ---------------- GEMM2: c = tanh(Xc@W_c + b); out = u*hx + (1-u)*c ----------------
__global__ __launch_bounds__(256, 2) void gemm_c_k(
        const u16* __restrict__ X, const u16* __restrict__ Wt, const float* __restrict__ b_c,
        const float* __restrict__ hx, const u16* __restrict__ U, float* __restrict__ out){
    __shared__ u16 sA[16384];
    const int t = threadIdx.x;
    const int lane = t & 63, w = t >> 6;
    const int cIn = lane & 15, q = lane >> 4;
    const int node0 = blockIdx.x * 8;
    const char* xbase = (const char*)X + (size_t)node0*ROWB;

    f32x4 acc[4][4];
    const f32x4 z4 = {0.f,0.f,0.f,0.f};
    #pragma unroll
    for (int rt = 0; rt < 4; ++rt)
        #pragma unroll
        for (int ct = 0; ct < 4; ++ct) acc[rt][ct] = z4;

    bf16x8 cb[4], nb[4];
    stage_step(xbase, 0, (char*)sA, t);
    #pragma unroll
    for (int ct = 0; ct < 4; ++ct)
        cb[ct] = *(const bf16x8*)&Wt[(ct*16 + cIn)*KLIN + q*8];
    __syncthreads();

    for (int j = 0; j < 12; ++j){
        const int cur = j & 1;
        if (j < 11){
            stage_step(xbase, j+1, (char*)sA + (cur^1)*16384, t);
            #pragma unroll
            for (int ct = 0; ct < 4; ++ct)
                nb[ct] = *(const bf16x8*)&Wt[(ct*16 + cIn)*KLIN + (j+1)*32 + q*8];
        }
        const u16* As = sA + cur*8192;
        #pragma unroll
        for (int rt = 0; rt < 4; ++rt){
            int nd = w*2 + (rt >> 1);
            int b  = (rt & 1)*16 + cIn;
            bf16x8 a = *(const bf16x8*)&As[nd*1024 + (q*32 + b)*8];
            #pragma unroll
            for (int ct = 0; ct < 4; ++ct)
                acc[rt][ct] = __builtin_amdgcn_mfma_f32_16x16x32_bf16(a, cb[ct], acc[rt][ct], 0,0,0);
        }
        #pragma unroll
        for (int ct = 0; ct < 4; ++ct) cb[ct] = nb[ct];
        __syncthreads();
    }

    #pragma unroll
    for (int ct = 0; ct < 4; ++ct){
        int col = ct*16 + cIn;
        float bias = b_c[col];
        #pragma unroll
        for (int rt = 0; rt < 4; ++rt){
            int nd = w*2 + (rt >> 1);
            int b0 = (rt & 1)*16 + q*4;
            int node = node0 + nd;
            f32x4 d = acc[rt][ct];
            uint2 up = *(const uint2*)&U[(size_t)node*2048 + col*32 + b0];
            float uu[4] = { lo16(up.x), hi16(up.x), lo16(up.y), hi16(up.y) };
            #pragma unroll
            for (int i = 0; i < 4; ++i){
                float c = tanhf(d[i] + bias);
                size_t gi = (size_t)(b0 + i)*HXROW + (size_t)node*64 + col;
                float h = hx[gi];
                out[gi] = uu[i]*h + (1.f - uu[i])*c;
            }
        }
    }
}

// ---------------- launch ----------------
extern "C" void kernel_launch(void* const* d_in, const int* in_sizes, int n_in,
                              void* d_out, int out_size, void* d_ws, size_t ws_size,
                              hipStream_t stream){
    const float* inputs = (const float*)d_in[0];
    const float* hx     = (const float*)d_in[1];
    const float* W_ru   = (const float*)d_in[2];
    const float* b_ru   = (const float*)d_in[3];
    const float* W_c    = (const float*)d_in[4];
    const float* b_c    = (const float*)d_in[5];
    const int*   s0r    = (const int*)d_in[6];
    const int*   s0c    = (const int*)d_in[7];
    const float* s0v    = (const float*)d_in[8];
    const int*   s1c    = (const int*)d_in[10];
    const float* s1v    = (const float*)d_in[11];
    float* out = (float*)d_out;

    char* ws = (char*)d_ws;
    size_t off = 0;
    auto alloc = [&](size_t bytes) -> char* {
        char* p = ws + off;
        off += (bytes + 255) & ~(size_t)255;
        return p;
    };
    u16* X    = (u16*)alloc((size_t)NNODES*ROWB);          // 196.6 MB concat
    u16* U    = (u16*)alloc((size_t)NNODES*2048*2);
    u16* WtRU = (u16*)alloc((size_t)128*KLIN*2);
    u16* WtC  = (u16*)alloc((size_t)64*KLIN*2);
    int* counts  = (int*)alloc((size_t)NNODES*4);
    int* row_ptr = (int*)alloc((size_t)(NNODES+1)*4);
    int* cursor  = (int*)alloc((size_t)NNODES*4);
    int*   cols_s = (int*)alloc((size_t)EDG*4);
    float* vals_s = (float*)alloc((size_t)EDG*4);
    (void)ws_size; (void)in_sizes; (void)n_in; (void)out_size;

    // CSR build for support 0
    hipMemsetAsync(counts, 0, (size_t)NNODES*4, stream);
    hist_k<<<250, 256, 0, stream>>>(s0r, counts);
    scan_k<<<1, 256, 0, stream>>>(counts, row_ptr, cursor);
    scatter_k<<<250, 256, 0, stream>>>(s0r, s0c, s0v, cursor, cols_s, vals_s);

    prep_w_k<<<288, 256, 0, stream>>>(W_ru, W_c, WtRU, WtC);
    build_x0_k<<<NNODES, 256, 0, stream>>>(inputs, hx, X);

    // gconv 1 diffusion: level1 (m=1 S0, m=3 S1), level2 (m=2, m=4)
    diff_k<<<9000, 256, 0, stream>>>(X, row_ptr, cols_s, vals_s, s1c, s1v, 0, 9, 0, 27, 0);
    diff_k<<<9000, 256, 0, stream>>>(X, row_ptr, cols_s, vals_s, s1c, s1v, 9, 18, 27, 36, 1);

    // GEMM1 + sigmoid; writes U and X state = r*hx
    gemm_ru_k<<<NNODES/8, 256, 0, stream>>>(X, WtRU, b_ru, U);

    // gconv 2 diffusion
    diff_k<<<9000, 256, 0, stream>>>(X, row_ptr, cols_s, vals_s, s1c, s1v, 0, 9, 0, 27, 0);
    diff_k<<<9000, 256, 0, stream>>>(X, row_ptr, cols_s, vals_s, s1c, s1v, 9, 18, 27, 36, 1);

    // GEMM2 + tanh + final gate
    gemm_c_k<<<NNODES/8, 256, 0, stream>>>(X, WtC, b_c, hx, U, out);
}